// Round 1
// baseline (137.421 us; speedup 1.0000x reference)
//
#include <hip/hip_runtime.h>

// SpatialMTP1Hop: per-center mean of per-edge MSE of out_head(H[dst]) vs target[dst],
// then mean over centers. Decomposed:
//   err_node[n] = mean_j (H[n]·W[:,j] + b[j] - target[n][j])^2        (per node, not per edge)
//   owner_of[node] = center slot (sentinel C otherwise)
//   per edge e=(s,d): if owner_of[s]<C: loss_sum[o]+=err_node[d]; cnt[o]+=1
//   out = mean_c loss_sum[c]/max(cnt[c],1)

#define D_DIM 128
#define DO_DIM 3

__global__ void err_node_kernel(const float* __restrict__ H,
                                const float* __restrict__ W,
                                const float* __restrict__ b,
                                const float* __restrict__ target,
                                float* __restrict__ err_node, int N) {
    int gtid = blockIdx.x * blockDim.x + threadIdx.x;
    int node = gtid >> 6;          // one wave (64 lanes) per node
    int lane = threadIdx.x & 63;
    if (node >= N) return;

    // coalesced 512B row read: lane reads float2 at elements [2*lane, 2*lane+1]
    const float2* h2 = reinterpret_cast<const float2*>(H + (size_t)node * D_DIM);
    float2 hv = h2[lane];
    int i0 = 2 * lane, i1 = 2 * lane + 1;

    float a0 = hv.x * W[i0 * DO_DIM + 0] + hv.y * W[i1 * DO_DIM + 0];
    float a1 = hv.x * W[i0 * DO_DIM + 1] + hv.y * W[i1 * DO_DIM + 1];
    float a2 = hv.x * W[i0 * DO_DIM + 2] + hv.y * W[i1 * DO_DIM + 2];

    // 64-lane butterfly reduction
    #pragma unroll
    for (int off = 32; off > 0; off >>= 1) {
        a0 += __shfl_down(a0, off, 64);
        a1 += __shfl_down(a1, off, 64);
        a2 += __shfl_down(a2, off, 64);
    }

    if (lane == 0) {
        float e0 = a0 + b[0] - target[(size_t)node * DO_DIM + 0];
        float e1 = a1 + b[1] - target[(size_t)node * DO_DIM + 1];
        float e2 = a2 + b[2] - target[(size_t)node * DO_DIM + 2];
        err_node[node] = (e0 * e0 + e1 * e1 + e2 * e2) * (1.0f / DO_DIM);
    }
}

__global__ void owner_init_kernel(int* __restrict__ owner_of, int N, int C) {
    int i = blockIdx.x * blockDim.x + threadIdx.x;
    if (i < N) owner_of[i] = C;   // sentinel
}

__global__ void owner_scatter_kernel(const int* __restrict__ centers,
                                     int* __restrict__ owner_of, int C) {
    int i = blockIdx.x * blockDim.x + threadIdx.x;
    if (i < C) owner_of[centers[i]] = i;
}

__global__ void edge_kernel(const int* __restrict__ edge_index,
                            const int* __restrict__ owner_of,
                            const float* __restrict__ err_node,
                            float* __restrict__ loss_sum,
                            float* __restrict__ cnt,
                            int E, int C) {
    int e = blockIdx.x * blockDim.x + threadIdx.x;
    if (e >= E) return;
    int s = edge_index[e];            // row 0: src
    int o = owner_of[s];
    if (o < C) {
        int d = edge_index[E + e];    // row 1: dst
        atomicAdd(&loss_sum[o], err_node[d]);
        atomicAdd(&cnt[o], 1.0f);
    }
}

__global__ void finalize_kernel(const float* __restrict__ loss_sum,
                                const float* __restrict__ cnt,
                                float* __restrict__ out, int C) {
    int i = blockIdx.x * blockDim.x + threadIdx.x;
    float v = 0.0f;
    if (i < C) v = loss_sum[i] / fmaxf(cnt[i], 1.0f);
    #pragma unroll
    for (int off = 32; off > 0; off >>= 1) v += __shfl_down(v, off, 64);
    if ((threadIdx.x & 63) == 0 && v != 0.0f) atomicAdd(out, v / (float)C);
}

extern "C" void kernel_launch(void* const* d_in, const int* in_sizes, int n_in,
                              void* d_out, int out_size, void* d_ws, size_t ws_size,
                              hipStream_t stream) {
    const float* H      = (const float*)d_in[0];
    const float* W      = (const float*)d_in[1];
    const float* b      = (const float*)d_in[2];
    const float* target = (const float*)d_in[3];
    const int*   eidx   = (const int*)d_in[4];
    const int*   ctrs   = (const int*)d_in[5];

    const int DO = in_sizes[2];          // 3
    const int D  = in_sizes[1] / DO;     // 128
    const int N  = in_sizes[0] / D;      // 100000
    const int E  = in_sizes[4] / 2;      // 1600000
    const int C  = in_sizes[5];          // 50000

    // workspace layout (all 256B-aligned)
    char* ws = (char*)d_ws;
    float* err_node = (float*)ws;                         ws += ((size_t)N * 4 + 255) & ~255ull;
    int*   owner_of = (int*)ws;                           ws += ((size_t)N * 4 + 255) & ~255ull;
    float* loss_sum = (float*)ws;                         ws += ((size_t)C * 4 + 255) & ~255ull;
    float* cnt      = (float*)ws;

    // zero accumulators + output every call (graph-capture-legal)
    hipMemsetAsync(loss_sum, 0, (size_t)C * 4, stream);
    hipMemsetAsync(cnt,      0, (size_t)C * 4, stream);
    hipMemsetAsync(d_out,    0, (size_t)out_size * 4, stream);

    // 1) per-node error: one wave per node
    {
        int waves_per_block = 4;                 // 256 threads
        int blocks = (N + waves_per_block - 1) / waves_per_block;
        err_node_kernel<<<blocks, 256, 0, stream>>>(H, W, b, target, err_node, N);
    }
    // 2) owner map
    owner_init_kernel<<<(N + 255) / 256, 256, 0, stream>>>(owner_of, N, C);
    owner_scatter_kernel<<<(C + 255) / 256, 256, 0, stream>>>(ctrs, owner_of, C);
    // 3) edge accumulation
    edge_kernel<<<(E + 255) / 256, 256, 0, stream>>>(eidx, owner_of, err_node,
                                                     loss_sum, cnt, E, C);
    // 4) final mean over centers
    finalize_kernel<<<(C + 255) / 256, 256, 0, stream>>>(loss_sum, cnt,
                                                         (float*)d_out, C);
}

// Round 2
// 73.172 us; speedup vs baseline: 1.8781x; 1.8781x over previous
//
#include <hip/hip_runtime.h>

// SpatialMTP1Hop decomposition:
//   err_node[n] = mean_j (H[n]·W[:,j] + b[j] - target[n][j])^2
//   owner_of[node] = center slot (sentinel C otherwise)
//   per edge e=(s,d): if owner_of[s]<C: bins[slot][o] += pack(cnt=1, err_node[d])
//   out = mean_c errsum[c]/max(cnt[c],1)
//
// Atomic traffic is the bottleneck (R1: WRITE_SIZE 49.9MB, 18G atomics/s).
// Fix: ONE packed u64 atomic per masked edge (count in bits[44:63], err as
// fixed-point 2^-26 in bits[0:44)), replicated R-way to spread cacheline
// contention. Max per-bin errsum ~2^37 << 2^44 so low field never carries
// into the count field.

#define D_DIM 128
#define ERR_SCALE 67108864.0f          // 2^26
#define CNT_SHIFT 44

// K1: per-node out_head MSE (32 lanes per node, float4 row loads)
//     + owner_of sentinel init (fused, independent store)
__global__ void err_node_kernel(const float* __restrict__ H,
                                const float* __restrict__ W,
                                const float* __restrict__ b,
                                const float* __restrict__ target,
                                float* __restrict__ err_node,
                                int* __restrict__ owner_of,
                                int N, int C) {
    int gtid = blockIdx.x * blockDim.x + threadIdx.x;
    if (gtid < N) owner_of[gtid] = C;          // fused sentinel init

    int lane = threadIdx.x & 63;
    int sub  = lane >> 5;                       // 2 nodes per wave
    int l32  = lane & 31;
    int node = (gtid >> 6) * 2 + sub;
    if (node >= N) return;

    const float4* h4 = reinterpret_cast<const float4*>(H + (size_t)node * D_DIM);
    float4 hv = h4[l32];                        // elements [4*l32 .. 4*l32+3]
    int i0 = 4 * l32;

    float a0 = 0.f, a1 = 0.f, a2 = 0.f;
    float hx[4] = {hv.x, hv.y, hv.z, hv.w};
    #pragma unroll
    for (int k = 0; k < 4; ++k) {
        float h = hx[k];
        const float* w = W + (size_t)(i0 + k) * 3;
        a0 += h * w[0];
        a1 += h * w[1];
        a2 += h * w[2];
    }
    // butterfly over the 32-lane subgroup (xor masks <32 stay in-half)
    #pragma unroll
    for (int m = 16; m > 0; m >>= 1) {
        a0 += __shfl_xor(a0, m, 64);
        a1 += __shfl_xor(a1, m, 64);
        a2 += __shfl_xor(a2, m, 64);
    }
    if (l32 == 0) {
        float e0 = a0 + b[0] - target[(size_t)node * 3 + 0];
        float e1 = a1 + b[1] - target[(size_t)node * 3 + 1];
        float e2 = a2 + b[2] - target[(size_t)node * 3 + 2];
        err_node[node] = (e0 * e0 + e1 * e1 + e2 * e2) * (1.0f / 3.0f);
    }
}

// K2: scatter center slots
__global__ void owner_scatter_kernel(const int* __restrict__ centers,
                                     int* __restrict__ owner_of, int C) {
    int i = blockIdx.x * blockDim.x + threadIdx.x;
    if (i < C) owner_of[centers[i]] = i;
}

// K3: one packed u64 atomic per masked edge into replicated bins
__global__ void edge_kernel(const int* __restrict__ edge_index,
                            const int* __restrict__ owner_of,
                            const float* __restrict__ err_node,
                            unsigned long long* __restrict__ bins,
                            int E, int C, int Rmask) {
    int e = blockIdx.x * blockDim.x + threadIdx.x;
    if (e >= E) return;
    int s = edge_index[e];                 // row 0: src
    int o = owner_of[s];
    if (o < C) {
        int d = edge_index[E + e];         // row 1: dst
        float err = err_node[d];
        unsigned long long add = (1ull << CNT_SHIFT)
                               + (unsigned long long)(err * ERR_SCALE);
        size_t slot = (size_t)(threadIdx.x & Rmask) * (size_t)C;
        atomicAdd(&bins[slot + o], add);
    }
}

// K4: sum replicas, per-center mean, grand mean
__global__ void finalize_kernel(const unsigned long long* __restrict__ bins,
                                float* __restrict__ out, int C, int R) {
    int i = blockIdx.x * blockDim.x + threadIdx.x;
    float term = 0.0f;
    if (i < C) {
        unsigned long long sum = 0ull;
        for (int r = 0; r < R; ++r) sum += bins[(size_t)r * C + i];
        float cnt = (float)(sum >> CNT_SHIFT);
        float es  = (float)(sum & ((1ull << CNT_SHIFT) - 1)) * (1.0f / ERR_SCALE);
        term = es / fmaxf(cnt, 1.0f);
    }
    #pragma unroll
    for (int m = 32; m > 0; m >>= 1) term += __shfl_down(term, m, 64);
    __shared__ float wsum[4];
    int lane = threadIdx.x & 63, w = threadIdx.x >> 6;
    if (lane == 0) wsum[w] = term;
    __syncthreads();
    if (threadIdx.x == 0) {
        float t = wsum[0] + wsum[1] + wsum[2] + wsum[3];
        atomicAdd(out, t / (float)C);
    }
}

extern "C" void kernel_launch(void* const* d_in, const int* in_sizes, int n_in,
                              void* d_out, int out_size, void* d_ws, size_t ws_size,
                              hipStream_t stream) {
    const float* H      = (const float*)d_in[0];
    const float* W      = (const float*)d_in[1];
    const float* b      = (const float*)d_in[2];
    const float* target = (const float*)d_in[3];
    const int*   eidx   = (const int*)d_in[4];
    const int*   ctrs   = (const int*)d_in[5];

    const int DO = in_sizes[2];          // 3
    const int D  = in_sizes[1] / DO;     // 128
    const int N  = in_sizes[0] / D;      // 100000
    const int E  = in_sizes[4] / 2;      // 1600000
    const int C  = in_sizes[5];          // 50000

    // workspace layout
    size_t off = 0;
    auto take = [&](size_t bytes) {
        void* p = (char*)d_ws + off;
        off = (off + bytes + 255) & ~255ull;
        return p;
    };
    float* err_node = (float*)take((size_t)N * 4);
    int*   owner_of = (int*)take((size_t)N * 4);
    size_t rem = (ws_size > off) ? (ws_size - off) : 0;
    int R = (int)(rem / ((size_t)C * 8));
    if (R >= 8) R = 8; else if (R >= 4) R = 4; else if (R >= 2) R = 2; else R = 1;
    unsigned long long* bins = (unsigned long long*)((char*)d_ws + off);

    hipMemsetAsync(bins, 0, (size_t)R * C * 8, stream);
    hipMemsetAsync(d_out, 0, (size_t)out_size * 4, stream);

    // K1: err_node + owner sentinel init (32 lanes/node -> N*32 threads)
    {
        long long threads = (long long)((N + 1) / 2) * 64;
        int blocks = (int)((threads + 255) / 256);
        err_node_kernel<<<blocks, 256, 0, stream>>>(H, W, b, target,
                                                    err_node, owner_of, N, C);
    }
    owner_scatter_kernel<<<(C + 255) / 256, 256, 0, stream>>>(ctrs, owner_of, C);
    edge_kernel<<<(E + 255) / 256, 256, 0, stream>>>(eidx, owner_of, err_node,
                                                     bins, E, C, R - 1);
    finalize_kernel<<<(C + 255) / 256, 256, 0, stream>>>(bins, (float*)d_out, C, R);
}

// Round 3
// 52.189 us; speedup vs baseline: 2.6331x; 1.4021x over previous
//
#include <hip/hip_runtime.h>

// SpatialMTP1Hop:
//   err_node[n] = mean_j (H[n]·W[:,j] + b[j] - target[n][j])^2
//   owner_of[node] = center slot (or -1)
//   per masked edge (s,d): center owner(s) accumulates (cnt, err_node[d])
//   out = mean_c errsum[c]/max(cnt[c],1)
//
// R2 showed global-atomic transaction count is THE cost (~37G atomics/s flat).
// R3: bucketed two-phase. K3 bins edges into 196 center-buckets with LDS
// histograms + one global cursor atomic per (block,bucket) (~50K atomics),
// scattering 4B packed (o&255,dst) pairs. K4 reduces each bucket in LDS u64
// bins (exact fixed-point), then per-center mean + one atomic per block.

#define CNT_SHIFT 44
#define ERR_SCALE 67108864.0f     // 2^26 fixed-point for err
#define BKT_SHIFT 8               // 256 centers per bucket
#define BKT_SIZE  256
#define CAP       8192            // slots per bucket (expected ~4080)
#define K3_THREADS 1024
#define K3_EPT     7              // max edges/thread for LDS stash

// K1: per-node out_head MSE (32 lanes/node, float4 loads)
//     + owner scatter (owner pre-set to -1 by memset) + cursor/out zeroing
__global__ __launch_bounds__(256)
void err_node_kernel(const float* __restrict__ H,
                     const float* __restrict__ W,
                     const float* __restrict__ b,
                     const float* __restrict__ target,
                     const int* __restrict__ centers,
                     float* __restrict__ err_node,
                     int* __restrict__ owner_of,
                     unsigned int* __restrict__ gcursor,
                     float* __restrict__ out,
                     int N, int C, int NB, int out_size) {
    int gtid = blockIdx.x * blockDim.x + threadIdx.x;
    if (gtid < C) owner_of[centers[gtid]] = gtid;   // no race: sentinel came from memset
    if (gtid < NB) gcursor[gtid] = 0u;
    if (gtid < out_size) out[gtid] = 0.f;

    int lane = threadIdx.x & 63;
    int sub  = lane >> 5;
    int l32  = lane & 31;
    int node = (gtid >> 6) * 2 + sub;
    if (node >= N) return;

    const float4* h4 = reinterpret_cast<const float4*>(H + (size_t)node * 128);
    float4 hv = h4[l32];
    int i0 = 4 * l32;
    float a0 = 0.f, a1 = 0.f, a2 = 0.f;
    float hx[4] = {hv.x, hv.y, hv.z, hv.w};
    #pragma unroll
    for (int k = 0; k < 4; ++k) {
        const float* w = W + (size_t)(i0 + k) * 3;
        a0 += hx[k] * w[0];
        a1 += hx[k] * w[1];
        a2 += hx[k] * w[2];
    }
    #pragma unroll
    for (int m = 16; m > 0; m >>= 1) {
        a0 += __shfl_xor(a0, m, 64);
        a1 += __shfl_xor(a1, m, 64);
        a2 += __shfl_xor(a2, m, 64);
    }
    if (l32 == 0) {
        float e0 = a0 + b[0] - target[(size_t)node * 3 + 0];
        float e1 = a1 + b[1] - target[(size_t)node * 3 + 1];
        float e2 = a2 + b[2] - target[(size_t)node * 3 + 2];
        err_node[node] = (e0 * e0 + e1 * e1 + e2 * e2) * (1.0f / 3.0f);
    }
}

// K3: bucketize masked edges into per-bucket pair arrays
__global__ __launch_bounds__(K3_THREADS)
void bucketize_kernel(const int* __restrict__ eidx,
                      const int* __restrict__ owner_of,
                      unsigned int* __restrict__ gcursor,
                      unsigned int* __restrict__ pairs,
                      int E, int NB) {
    __shared__ unsigned long long stash[K3_THREADS * K3_EPT];
    __shared__ unsigned int hist[256];
    __shared__ unsigned int base[256];
    int t = threadIdx.x;
    int chunk = (E + gridDim.x - 1) / gridDim.x;
    int start = blockIdx.x * chunk;
    int end   = min(E, start + chunk);
    if (t < NB) hist[t] = 0u;
    __syncthreads();

    int nk = 0;
    for (int e = start + t; e < end; e += K3_THREADS) {
        unsigned long long v = ~0ull;
        int s = eidx[e];                 // row 0: src
        int o = owner_of[s];
        if (o >= 0) {
            int d = eidx[E + e];         // row 1: dst
            v = ((unsigned long long)(unsigned)o << 17) | (unsigned)d;
            atomicAdd(&hist[(unsigned)o >> BKT_SHIFT], 1u);
        }
        stash[nk * K3_THREADS + t] = v;
        ++nk;
    }
    __syncthreads();
    if (t < NB) {
        unsigned int h = hist[t];
        base[t] = h ? atomicAdd(&gcursor[t], h) : 0u;
        hist[t] = 0u;                    // reuse as local cursor
    }
    __syncthreads();
    for (int k = 0; k < nk; ++k) {
        unsigned long long v = stash[k * K3_THREADS + t];
        if (v != ~0ull) {
            unsigned int o = (unsigned int)(v >> 17);
            unsigned int bk = o >> BKT_SHIFT;
            unsigned int slot = base[bk] + atomicAdd(&hist[bk], 1u);
            if (slot < CAP)
                pairs[(size_t)bk * CAP + slot] =
                    ((o & (BKT_SIZE - 1)) << 17) | (unsigned int)(v & 0x1FFFFull);
        }
    }
}

// K4: per-bucket LDS reduction + per-center mean + grand sum
__global__ __launch_bounds__(256)
void reduce_kernel(const unsigned int* __restrict__ pairs,
                   const unsigned int* __restrict__ gcursor,
                   const float* __restrict__ err_node,
                   float* __restrict__ out, int C, float invC) {
    __shared__ unsigned long long bins[BKT_SIZE];
    int bk = blockIdx.x, t = threadIdx.x;
    bins[t] = 0ull;
    __syncthreads();
    unsigned int count = gcursor[bk];
    if (count > CAP) count = CAP;
    for (unsigned int i = t; i < count; i += 256) {
        unsigned int p = pairs[(size_t)bk * CAP + i];
        unsigned int oin = p >> 17;
        unsigned int d   = p & 0x1FFFFu;
        float err = err_node[d];
        atomicAdd(&bins[oin],
                  (1ull << CNT_SHIFT) + (unsigned long long)(err * ERR_SCALE));
    }
    __syncthreads();
    int center = bk * BKT_SIZE + t;
    float term = 0.f;
    if (center < C) {
        unsigned long long u = bins[t];
        float cnt = (float)(u >> CNT_SHIFT);
        float es  = (float)(u & ((1ull << CNT_SHIFT) - 1)) * (1.0f / ERR_SCALE);
        term = es / fmaxf(cnt, 1.0f);
    }
    #pragma unroll
    for (int m = 32; m > 0; m >>= 1) term += __shfl_down(term, m, 64);
    __shared__ float wsum[4];
    if ((t & 63) == 0) wsum[t >> 6] = term;
    __syncthreads();
    if (t == 0)
        atomicAdd(out, (wsum[0] + wsum[1] + wsum[2] + wsum[3]) * invC);
}

// ---- fallback path (R2-style) if workspace too small for pairs buffer ----
__global__ void edge_atomic_kernel(const int* __restrict__ eidx,
                                   const int* __restrict__ owner_of,
                                   const float* __restrict__ err_node,
                                   unsigned long long* __restrict__ bins,
                                   int E, int C, int Rmask) {
    int e = blockIdx.x * blockDim.x + threadIdx.x;
    if (e >= E) return;
    int s = eidx[e];
    int o = owner_of[s];
    if (o >= 0) {
        int d = eidx[E + e];
        unsigned long long add = (1ull << CNT_SHIFT)
                               + (unsigned long long)(err_node[d] * ERR_SCALE);
        atomicAdd(&bins[(size_t)(threadIdx.x & Rmask) * C + o], add);
    }
}

__global__ void finalize_kernel(const unsigned long long* __restrict__ bins,
                                float* __restrict__ out, int C, int R) {
    int i = blockIdx.x * blockDim.x + threadIdx.x;
    float term = 0.f;
    if (i < C) {
        unsigned long long sum = 0ull;
        for (int r = 0; r < R; ++r) sum += bins[(size_t)r * C + i];
        float cnt = (float)(sum >> CNT_SHIFT);
        float es  = (float)(sum & ((1ull << CNT_SHIFT) - 1)) * (1.0f / ERR_SCALE);
        term = es / fmaxf(cnt, 1.0f);
    }
    #pragma unroll
    for (int m = 32; m > 0; m >>= 1) term += __shfl_down(term, m, 64);
    __shared__ float wsum[4];
    if ((threadIdx.x & 63) == 0) wsum[threadIdx.x >> 6] = term;
    __syncthreads();
    if (threadIdx.x == 0)
        atomicAdd(out, (wsum[0] + wsum[1] + wsum[2] + wsum[3]) / (float)C);
}

extern "C" void kernel_launch(void* const* d_in, const int* in_sizes, int n_in,
                              void* d_out, int out_size, void* d_ws, size_t ws_size,
                              hipStream_t stream) {
    const float* H      = (const float*)d_in[0];
    const float* W      = (const float*)d_in[1];
    const float* b      = (const float*)d_in[2];
    const float* target = (const float*)d_in[3];
    const int*   eidx   = (const int*)d_in[4];
    const int*   ctrs   = (const int*)d_in[5];

    const int DO = in_sizes[2];
    const int D  = in_sizes[1] / DO;     // 128
    const int N  = in_sizes[0] / D;      // 100000
    const int E  = in_sizes[4] / 2;      // 1600000
    const int C  = in_sizes[5];          // 50000
    const int NB = (C + BKT_SIZE - 1) >> BKT_SHIFT;   // 196

    size_t off = 0;
    auto take = [&](size_t bytes) {
        void* p = (char*)d_ws + off;
        off = (off + bytes + 255) & ~255ull;
        return p;
    };
    float* err_node = (float*)take((size_t)N * 4);
    int*   owner_of = (int*)take((size_t)N * 4);
    unsigned int* gcursor = (unsigned int*)take((size_t)NB * 4);
    unsigned int* pairs   = (unsigned int*)((char*)d_ws + off);
    size_t need = off + (size_t)NB * CAP * 4;

    // owner sentinel = -1 via byte pattern; safe to fold scatter into K1
    hipMemsetAsync(owner_of, 0xFF, (size_t)N * 4, stream);

    {
        long long threads = (long long)((N + 1) / 2) * 64;
        int blocks = (int)((threads + 255) / 256);
        err_node_kernel<<<blocks, 256, 0, stream>>>(H, W, b, target, ctrs,
                                                    err_node, owner_of, gcursor,
                                                    (float*)d_out, N, C, NB, out_size);
    }

    bool fits = (ws_size >= need) && (NB <= 256) && (C < (1 << 16)) && (N < (1 << 17));
    if (fits) {
        bucketize_kernel<<<256, K3_THREADS, 0, stream>>>(eidx, owner_of,
                                                         gcursor, pairs, E, NB);
        reduce_kernel<<<NB, 256, 0, stream>>>(pairs, gcursor, err_node,
                                              (float*)d_out, C, 1.0f / (float)C);
    } else {
        size_t rem = (ws_size > off) ? ws_size - off : 0;
        int R = (int)(rem / ((size_t)C * 8));
        if (R >= 8) R = 8; else if (R >= 4) R = 4; else if (R >= 2) R = 2; else R = 1;
        unsigned long long* bins = (unsigned long long*)((char*)d_ws + off);
        hipMemsetAsync(bins, 0, (size_t)R * C * 8, stream);
        edge_atomic_kernel<<<(E + 255) / 256, 256, 0, stream>>>(eidx, owner_of,
                                                                err_node, bins,
                                                                E, C, R - 1);
        finalize_kernel<<<(C + 255) / 256, 256, 0, stream>>>(bins, (float*)d_out, C, R);
    }
}

// Round 4
// 48.562 us; speedup vs baseline: 2.8298x; 1.0747x over previous
//
#include <hip/hip_runtime.h>

// SpatialMTP1Hop:
//   err_node[n] = mean_j (H[n]·W[:,j] + b[j] - target[n][j])^2
//   owner_of[node] = center slot (or -1)
//   per masked edge (s,d): center owner(s) accumulates (cnt, err_node[d])
//   out = mean_c errsum[c]/max(cnt[c],1)
//
// R3 postmortem: the hipMemsetAsync(owner_of,0xFF,400KB) fill kernel ran at
// 10 GB/s = 39.6us — the LARGEST dispatch in the graph. R4: no memsets in the
// timed graph at all. K1 fuses sentinel init + gcursor/out zeroing; K2 is a
// tiny center scatter; K3 buckets edges (LDS hist + ~50K cursor atomics);
// K4 reduces per-bucket in LDS u64 fixed-point bins (exact, deterministic).

#define CNT_SHIFT 44
#define ERR_SCALE 67108864.0f     // 2^26 fixed-point for err
#define BKT_SHIFT 8               // 256 centers per bucket
#define BKT_SIZE  256
#define CAP       8192            // slots per bucket (expected ~4080)
#define K3_THREADS 1024
#define K3_EPT     7              // max edges/thread for LDS stash

// K1: per-node out_head MSE (32 lanes/node, float4 loads)
//     + owner sentinel init + gcursor/out zeroing (independent stores)
__global__ __launch_bounds__(256)
void err_node_kernel(const float* __restrict__ H,
                     const float* __restrict__ W,
                     const float* __restrict__ b,
                     const float* __restrict__ target,
                     float* __restrict__ err_node,
                     int* __restrict__ owner_of,
                     unsigned int* __restrict__ gcursor,
                     float* __restrict__ out,
                     int N, int NB, int out_size) {
    int gtid = blockIdx.x * blockDim.x + threadIdx.x;
    if (gtid < N) owner_of[gtid] = -1;     // sentinel (scatter comes in K2)
    if (gtid < NB) gcursor[gtid] = 0u;
    if (gtid < out_size) out[gtid] = 0.f;

    int lane = threadIdx.x & 63;
    int sub  = lane >> 5;
    int l32  = lane & 31;
    int node = (gtid >> 6) * 2 + sub;
    if (node >= N) return;

    const float4* h4 = reinterpret_cast<const float4*>(H + (size_t)node * 128);
    float4 hv = h4[l32];
    int i0 = 4 * l32;
    float a0 = 0.f, a1 = 0.f, a2 = 0.f;
    float hx[4] = {hv.x, hv.y, hv.z, hv.w};
    #pragma unroll
    for (int k = 0; k < 4; ++k) {
        const float* w = W + (size_t)(i0 + k) * 3;
        a0 += hx[k] * w[0];
        a1 += hx[k] * w[1];
        a2 += hx[k] * w[2];
    }
    #pragma unroll
    for (int m = 16; m > 0; m >>= 1) {
        a0 += __shfl_xor(a0, m, 64);
        a1 += __shfl_xor(a1, m, 64);
        a2 += __shfl_xor(a2, m, 64);
    }
    if (l32 == 0) {
        float e0 = a0 + b[0] - target[(size_t)node * 3 + 0];
        float e1 = a1 + b[1] - target[(size_t)node * 3 + 1];
        float e2 = a2 + b[2] - target[(size_t)node * 3 + 2];
        err_node[node] = (e0 * e0 + e1 * e1 + e2 * e2) * (1.0f / 3.0f);
    }
}

// K2: scatter center slots (after K1's sentinel init)
__global__ __launch_bounds__(256)
void owner_scatter_kernel(const int* __restrict__ centers,
                          int* __restrict__ owner_of, int C) {
    int i = blockIdx.x * blockDim.x + threadIdx.x;
    if (i < C) owner_of[centers[i]] = i;
}

// K3: bucketize masked edges into per-bucket pair arrays
__global__ __launch_bounds__(K3_THREADS)
void bucketize_kernel(const int* __restrict__ eidx,
                      const int* __restrict__ owner_of,
                      unsigned int* __restrict__ gcursor,
                      unsigned int* __restrict__ pairs,
                      int E, int NB) {
    __shared__ unsigned long long stash[K3_THREADS * K3_EPT];
    __shared__ unsigned int hist[256];
    __shared__ unsigned int base[256];
    int t = threadIdx.x;
    int chunk = (E + gridDim.x - 1) / gridDim.x;
    int start = blockIdx.x * chunk;
    int end   = min(E, start + chunk);
    if (t < NB) hist[t] = 0u;
    __syncthreads();

    int nk = 0;
    for (int e = start + t; e < end; e += K3_THREADS) {
        unsigned long long v = ~0ull;
        int s = eidx[e];                 // row 0: src
        int o = owner_of[s];
        if (o >= 0) {
            int d = eidx[E + e];         // row 1: dst
            v = ((unsigned long long)(unsigned)o << 17) | (unsigned)d;
            atomicAdd(&hist[(unsigned)o >> BKT_SHIFT], 1u);
        }
        stash[nk * K3_THREADS + t] = v;
        ++nk;
    }
    __syncthreads();
    if (t < NB) {
        unsigned int h = hist[t];
        base[t] = h ? atomicAdd(&gcursor[t], h) : 0u;
        hist[t] = 0u;                    // reuse as local cursor
    }
    __syncthreads();
    for (int k = 0; k < nk; ++k) {
        unsigned long long v = stash[k * K3_THREADS + t];
        if (v != ~0ull) {
            unsigned int o = (unsigned int)(v >> 17);
            unsigned int bk = o >> BKT_SHIFT;
            unsigned int slot = base[bk] + atomicAdd(&hist[bk], 1u);
            if (slot < CAP)
                pairs[(size_t)bk * CAP + slot] =
                    ((o & (BKT_SIZE - 1)) << 17) | (unsigned int)(v & 0x1FFFFull);
        }
    }
}

// K4: per-bucket LDS reduction + per-center mean + grand sum
__global__ __launch_bounds__(256)
void reduce_kernel(const unsigned int* __restrict__ pairs,
                   const unsigned int* __restrict__ gcursor,
                   const float* __restrict__ err_node,
                   float* __restrict__ out, int C, float invC) {
    __shared__ unsigned long long bins[BKT_SIZE];
    int bk = blockIdx.x, t = threadIdx.x;
    bins[t] = 0ull;
    __syncthreads();
    unsigned int count = gcursor[bk];
    if (count > CAP) count = CAP;
    for (unsigned int i = t; i < count; i += 256) {
        unsigned int p = pairs[(size_t)bk * CAP + i];
        unsigned int oin = p >> 17;
        unsigned int d   = p & 0x1FFFFu;
        float err = err_node[d];
        atomicAdd(&bins[oin],
                  (1ull << CNT_SHIFT) + (unsigned long long)(err * ERR_SCALE));
    }
    __syncthreads();
    int center = bk * BKT_SIZE + t;
    float term = 0.f;
    if (center < C) {
        unsigned long long u = bins[t];
        float cnt = (float)(u >> CNT_SHIFT);
        float es  = (float)(u & ((1ull << CNT_SHIFT) - 1)) * (1.0f / ERR_SCALE);
        term = es / fmaxf(cnt, 1.0f);
    }
    #pragma unroll
    for (int m = 32; m > 0; m >>= 1) term += __shfl_down(term, m, 64);
    __shared__ float wsum[4];
    if ((t & 63) == 0) wsum[t >> 6] = term;
    __syncthreads();
    if (t == 0)
        atomicAdd(out, (wsum[0] + wsum[1] + wsum[2] + wsum[3]) * invC);
}

// ---- fallback path (R2-style) if workspace too small for pairs buffer ----
__global__ void edge_atomic_kernel(const int* __restrict__ eidx,
                                   const int* __restrict__ owner_of,
                                   const float* __restrict__ err_node,
                                   unsigned long long* __restrict__ bins,
                                   int E, int C, int Rmask) {
    int e = blockIdx.x * blockDim.x + threadIdx.x;
    if (e >= E) return;
    int s = eidx[e];
    int o = owner_of[s];
    if (o >= 0) {
        int d = eidx[E + e];
        unsigned long long add = (1ull << CNT_SHIFT)
                               + (unsigned long long)(err_node[d] * ERR_SCALE);
        atomicAdd(&bins[(size_t)(threadIdx.x & Rmask) * C + o], add);
    }
}

__global__ void finalize_kernel(const unsigned long long* __restrict__ bins,
                                float* __restrict__ out, int C, int R) {
    int i = blockIdx.x * blockDim.x + threadIdx.x;
    float term = 0.f;
    if (i < C) {
        unsigned long long sum = 0ull;
        for (int r = 0; r < R; ++r) sum += bins[(size_t)r * C + i];
        float cnt = (float)(sum >> CNT_SHIFT);
        float es  = (float)(sum & ((1ull << CNT_SHIFT) - 1)) * (1.0f / ERR_SCALE);
        term = es / fmaxf(cnt, 1.0f);
    }
    #pragma unroll
    for (int m = 32; m > 0; m >>= 1) term += __shfl_down(term, m, 64);
    __shared__ float wsum[4];
    if ((threadIdx.x & 63) == 0) wsum[threadIdx.x >> 6] = term;
    __syncthreads();
    if (threadIdx.x == 0)
        atomicAdd(out, (wsum[0] + wsum[1] + wsum[2] + wsum[3]) / (float)C);
}

extern "C" void kernel_launch(void* const* d_in, const int* in_sizes, int n_in,
                              void* d_out, int out_size, void* d_ws, size_t ws_size,
                              hipStream_t stream) {
    const float* H      = (const float*)d_in[0];
    const float* W      = (const float*)d_in[1];
    const float* b      = (const float*)d_in[2];
    const float* target = (const float*)d_in[3];
    const int*   eidx   = (const int*)d_in[4];
    const int*   ctrs   = (const int*)d_in[5];

    const int DO = in_sizes[2];
    const int D  = in_sizes[1] / DO;     // 128
    const int N  = in_sizes[0] / D;      // 100000
    const int E  = in_sizes[4] / 2;      // 1600000
    const int C  = in_sizes[5];          // 50000
    const int NB = (C + BKT_SIZE - 1) >> BKT_SHIFT;   // 196

    size_t off = 0;
    auto take = [&](size_t bytes) {
        void* p = (char*)d_ws + off;
        off = (off + bytes + 255) & ~255ull;
        return p;
    };
    float* err_node = (float*)take((size_t)N * 4);
    int*   owner_of = (int*)take((size_t)N * 4);
    unsigned int* gcursor = (unsigned int*)take((size_t)NB * 4);
    unsigned int* pairs   = (unsigned int*)((char*)d_ws + off);
    size_t need = off + (size_t)NB * CAP * 4;

    // K1: err_node + sentinel init + gcursor/out zeroing (no memsets!)
    {
        long long threads = (long long)((N + 1) / 2) * 64;
        int blocks = (int)((threads + 255) / 256);
        err_node_kernel<<<blocks, 256, 0, stream>>>(H, W, b, target,
                                                    err_node, owner_of, gcursor,
                                                    (float*)d_out, N, NB, out_size);
    }
    // K2: center scatter (ordered after K1 on the stream)
    owner_scatter_kernel<<<(C + 255) / 256, 256, 0, stream>>>(ctrs, owner_of, C);

    bool fits = (ws_size >= need) && (NB <= 256) && (C < (1 << 16)) && (N < (1 << 17));
    if (fits) {
        bucketize_kernel<<<256, K3_THREADS, 0, stream>>>(eidx, owner_of,
                                                         gcursor, pairs, E, NB);
        reduce_kernel<<<NB, 256, 0, stream>>>(pairs, gcursor, err_node,
                                              (float*)d_out, C, 1.0f / (float)C);
    } else {
        size_t rem = (ws_size > off) ? ws_size - off : 0;
        int R = (int)(rem / ((size_t)C * 8));
        if (R >= 8) R = 8; else if (R >= 4) R = 4; else if (R >= 2) R = 2; else R = 1;
        unsigned long long* bins = (unsigned long long*)((char*)d_ws + off);
        hipMemsetAsync(bins, 0, (size_t)R * C * 8, stream);
        edge_atomic_kernel<<<(E + 255) / 256, 256, 0, stream>>>(eidx, owner_of,
                                                                err_node, bins,
                                                                E, C, R - 1);
        finalize_kernel<<<(C + 255) / 256, 256, 0, stream>>>(bins, (float*)d_out, C, R);
    }
}

// Round 5
// 40.811 us; speedup vs baseline: 3.3672x; 1.1899x over previous
//
#include <hip/hip_runtime.h>

// SpatialMTP1Hop:
//   err_node[n] = mean_j (H[n]·W[:,j] + b[j] - target[n][j])^2
//   owner_of[node] = center slot (or -1); here centers==arange(C) so
//     owner(s) = (s<C ? s : -1) -- validated at runtime by K2 (ballot+atomicAnd
//     into `flag`), with a gather fallback for general inputs.
//   per masked edge (s,d): center owner(s) accumulates (cnt, err_node[d])
//   out = mean_c errsum[c]/max(cnt[c],1)
//
// Pipeline (no memsets in graph): K1 err_node + inits; K2 scatter + arange
// check; K3 bucketize (int4 edge reads, 2-pass recompute, 2KB LDS, ~50K
// global cursor atomics); K4 per-bucket LDS u64 fixed-point reduce (exact).

#define CNT_SHIFT 44
#define ERR_SCALE 67108864.0f     // 2^26 fixed-point for err
#define BKT_SHIFT 8               // 256 centers per bucket
#define BKT_SIZE  256
#define CAP       8192            // slots per bucket (expected ~4080)
#define K3_BLOCKS 256
#define K3_THREADS 1024

// K1: per-node out_head MSE (32 lanes/node, float4 loads)
//     + owner sentinel init + gcursor/out/flag init (independent stores)
__global__ __launch_bounds__(256)
void err_node_kernel(const float* __restrict__ H,
                     const float* __restrict__ W,
                     const float* __restrict__ b,
                     const float* __restrict__ target,
                     float* __restrict__ err_node,
                     int* __restrict__ owner_of,
                     unsigned int* __restrict__ gcursor,
                     int* __restrict__ flag,
                     float* __restrict__ out,
                     int N, int NB, int out_size) {
    int gtid = blockIdx.x * blockDim.x + threadIdx.x;
    if (gtid < N) owner_of[gtid] = -1;     // sentinel (scatter comes in K2)
    if (gtid < NB) gcursor[gtid] = 0u;
    if (gtid < out_size) out[gtid] = 0.f;
    if (gtid == 0) *flag = 1;              // "centers==arange" until disproven

    int lane = threadIdx.x & 63;
    int sub  = lane >> 5;
    int l32  = lane & 31;
    int node = (gtid >> 6) * 2 + sub;
    if (node >= N) return;

    const float4* h4 = reinterpret_cast<const float4*>(H + (size_t)node * 128);
    float4 hv = h4[l32];
    int i0 = 4 * l32;
    float a0 = 0.f, a1 = 0.f, a2 = 0.f;
    float hx[4] = {hv.x, hv.y, hv.z, hv.w};
    #pragma unroll
    for (int k = 0; k < 4; ++k) {
        const float* w = W + (size_t)(i0 + k) * 3;
        a0 += hx[k] * w[0];
        a1 += hx[k] * w[1];
        a2 += hx[k] * w[2];
    }
    #pragma unroll
    for (int m = 16; m > 0; m >>= 1) {
        a0 += __shfl_xor(a0, m, 64);
        a1 += __shfl_xor(a1, m, 64);
        a2 += __shfl_xor(a2, m, 64);
    }
    if (l32 == 0) {
        float e0 = a0 + b[0] - target[(size_t)node * 3 + 0];
        float e1 = a1 + b[1] - target[(size_t)node * 3 + 1];
        float e2 = a2 + b[2] - target[(size_t)node * 3 + 2];
        err_node[node] = (e0 * e0 + e1 * e1 + e2 * e2) * (1.0f / 3.0f);
    }
}

// K2: scatter center slots + validate centers==arange (wave ballot, rare atomics)
__global__ __launch_bounds__(256)
void owner_scatter_kernel(const int* __restrict__ centers,
                          int* __restrict__ owner_of,
                          int* __restrict__ flag, int C) {
    int i = blockIdx.x * blockDim.x + threadIdx.x;
    bool mismatch = false;
    if (i < C) {
        int c = centers[i];
        owner_of[c] = i;
        mismatch = (c != i);
    }
    unsigned long long m = __ballot(mismatch);
    if (m != 0ull && (threadIdx.x & 63) == 0) atomicAnd(flag, 0);
}

// K3: bucketize masked edges (int4 reads, two-pass recompute, 2KB LDS)
__global__ __launch_bounds__(K3_THREADS)
void bucketize_kernel(const int* __restrict__ eidx,
                      const int* __restrict__ owner_of,
                      const int* __restrict__ flag,
                      unsigned int* __restrict__ gcursor,
                      unsigned int* __restrict__ pairs,
                      int E, int C, int NB) {
    __shared__ unsigned int hist[256];
    __shared__ unsigned int base[256];
    int t = threadIdx.x;
    bool fast = (*flag != 0);                    // uniform across block
    int E4 = E >> 2;
    int chunk4 = (E4 + K3_BLOCKS - 1) / K3_BLOCKS;
    int c0 = blockIdx.x * chunk4;
    int c1 = min(E4, c0 + chunk4);
    if (t < 256) hist[t] = 0u;
    __syncthreads();

    const int4* row0 = reinterpret_cast<const int4*>(eidx);
    const int4* row1 = reinterpret_cast<const int4*>(eidx + E);

    for (int i = c0 + t; i < c1; i += K3_THREADS) {
        int4 s4 = row0[i];
        int ss[4] = {s4.x, s4.y, s4.z, s4.w};
        #pragma unroll
        for (int k = 0; k < 4; ++k) {
            int o = fast ? (ss[k] < C ? ss[k] : -1) : owner_of[ss[k]];
            if (o >= 0) atomicAdd(&hist[(unsigned)o >> BKT_SHIFT], 1u);
        }
    }
    __syncthreads();
    if (t < NB) {
        unsigned int h = hist[t];
        base[t] = h ? atomicAdd(&gcursor[t], h) : 0u;
        hist[t] = 0u;                            // reuse as local cursor
    }
    __syncthreads();
    for (int i = c0 + t; i < c1; i += K3_THREADS) {
        int4 s4 = row0[i];
        int4 d4 = row1[i];
        int ss[4] = {s4.x, s4.y, s4.z, s4.w};
        int dd[4] = {d4.x, d4.y, d4.z, d4.w};
        #pragma unroll
        for (int k = 0; k < 4; ++k) {
            int o = fast ? (ss[k] < C ? ss[k] : -1) : owner_of[ss[k]];
            if (o >= 0) {
                unsigned int bk = (unsigned)o >> BKT_SHIFT;
                unsigned int slot = base[bk] + atomicAdd(&hist[bk], 1u);
                if (slot < CAP)
                    pairs[(size_t)bk * CAP + slot] =
                        (((unsigned)o & (BKT_SIZE - 1)) << 17) | (unsigned)dd[k];
            }
        }
    }
}

// K4: per-bucket LDS u64 reduction + per-center mean + grand sum
__global__ __launch_bounds__(512)
void reduce_kernel(const unsigned int* __restrict__ pairs,
                   const unsigned int* __restrict__ gcursor,
                   const float* __restrict__ err_node,
                   float* __restrict__ out, int C, float invC) {
    __shared__ unsigned long long bins[BKT_SIZE];
    int bk = blockIdx.x, t = threadIdx.x;
    if (t < BKT_SIZE) bins[t] = 0ull;
    __syncthreads();
    unsigned int count = gcursor[bk];
    if (count > CAP) count = CAP;
    for (unsigned int i = t; i < count; i += 512) {
        unsigned int p = pairs[(size_t)bk * CAP + i];
        float err = err_node[p & 0x1FFFFu];
        atomicAdd(&bins[p >> 17],
                  (1ull << CNT_SHIFT) + (unsigned long long)(err * ERR_SCALE));
    }
    __syncthreads();
    float term = 0.f;
    if (t < BKT_SIZE) {
        int center = bk * BKT_SIZE + t;
        if (center < C) {
            unsigned long long u = bins[t];
            float cnt = (float)(u >> CNT_SHIFT);
            float es  = (float)(u & ((1ull << CNT_SHIFT) - 1)) * (1.0f / ERR_SCALE);
            term = es / fmaxf(cnt, 1.0f);
        }
    }
    #pragma unroll
    for (int m = 32; m > 0; m >>= 1) term += __shfl_down(term, m, 64);
    __shared__ float wsum[8];
    if ((t & 63) == 0) wsum[t >> 6] = term;
    __syncthreads();
    if (t == 0) {
        float s = 0.f;
        #pragma unroll
        for (int w = 0; w < 8; ++w) s += wsum[w];
        atomicAdd(out, s * invC);
    }
}

// ---- fallback path (R2-style) if workspace too small / shapes unexpected ----
__global__ void edge_atomic_kernel(const int* __restrict__ eidx,
                                   const int* __restrict__ owner_of,
                                   const float* __restrict__ err_node,
                                   unsigned long long* __restrict__ bins,
                                   int E, int C, int Rmask) {
    int e = blockIdx.x * blockDim.x + threadIdx.x;
    if (e >= E) return;
    int s = eidx[e];
    int o = owner_of[s];
    if (o >= 0) {
        int d = eidx[E + e];
        unsigned long long add = (1ull << CNT_SHIFT)
                               + (unsigned long long)(err_node[d] * ERR_SCALE);
        atomicAdd(&bins[(size_t)(threadIdx.x & Rmask) * C + o], add);
    }
}

__global__ void finalize_kernel(const unsigned long long* __restrict__ bins,
                                float* __restrict__ out, int C, int R) {
    int i = blockIdx.x * blockDim.x + threadIdx.x;
    float term = 0.f;
    if (i < C) {
        unsigned long long sum = 0ull;
        for (int r = 0; r < R; ++r) sum += bins[(size_t)r * C + i];
        float cnt = (float)(sum >> CNT_SHIFT);
        float es  = (float)(sum & ((1ull << CNT_SHIFT) - 1)) * (1.0f / ERR_SCALE);
        term = es / fmaxf(cnt, 1.0f);
    }
    #pragma unroll
    for (int m = 32; m > 0; m >>= 1) term += __shfl_down(term, m, 64);
    __shared__ float wsum[4];
    if ((threadIdx.x & 63) == 0) wsum[threadIdx.x >> 6] = term;
    __syncthreads();
    if (threadIdx.x == 0)
        atomicAdd(out, (wsum[0] + wsum[1] + wsum[2] + wsum[3]) / (float)C);
}

extern "C" void kernel_launch(void* const* d_in, const int* in_sizes, int n_in,
                              void* d_out, int out_size, void* d_ws, size_t ws_size,
                              hipStream_t stream) {
    const float* H      = (const float*)d_in[0];
    const float* W      = (const float*)d_in[1];
    const float* b      = (const float*)d_in[2];
    const float* target = (const float*)d_in[3];
    const int*   eidx   = (const int*)d_in[4];
    const int*   ctrs   = (const int*)d_in[5];

    const int DO = in_sizes[2];
    const int D  = in_sizes[1] / DO;     // 128
    const int N  = in_sizes[0] / D;      // 100000
    const int E  = in_sizes[4] / 2;      // 1600000
    const int C  = in_sizes[5];          // 50000
    const int NB = (C + BKT_SIZE - 1) >> BKT_SHIFT;   // 196

    size_t off = 0;
    auto take = [&](size_t bytes) {
        void* p = (char*)d_ws + off;
        off = (off + bytes + 255) & ~255ull;
        return p;
    };
    float* err_node = (float*)take((size_t)N * 4);
    int*   owner_of = (int*)take((size_t)N * 4);
    unsigned int* gcursor = (unsigned int*)take((size_t)NB * 4);
    int*   flag   = (int*)take(256);
    unsigned int* pairs = (unsigned int*)((char*)d_ws + off);
    size_t need = off + (size_t)NB * CAP * 4;

    // K1: err_node + sentinel/cursor/out/flag init (no memsets in graph)
    {
        long long threads = (long long)((N + 1) / 2) * 64;
        int blocks = (int)((threads + 255) / 256);
        err_node_kernel<<<blocks, 256, 0, stream>>>(H, W, b, target,
                                                    err_node, owner_of, gcursor,
                                                    flag, (float*)d_out,
                                                    N, NB, out_size);
    }
    // K2: center scatter + arange validation
    owner_scatter_kernel<<<(C + 255) / 256, 256, 0, stream>>>(ctrs, owner_of,
                                                              flag, C);

    bool fits = (ws_size >= need) && (NB <= 256) && (C < (1 << 16)) &&
                (N < (1 << 17)) && ((E & 3) == 0);
    if (fits) {
        bucketize_kernel<<<K3_BLOCKS, K3_THREADS, 0, stream>>>(eidx, owner_of,
                                                               flag, gcursor,
                                                               pairs, E, C, NB);
        reduce_kernel<<<NB, 512, 0, stream>>>(pairs, gcursor, err_node,
                                              (float*)d_out, C, 1.0f / (float)C);
    } else {
        size_t rem = (ws_size > off) ? ws_size - off : 0;
        int R = (int)(rem / ((size_t)C * 8));
        if (R >= 8) R = 8; else if (R >= 4) R = 4; else if (R >= 2) R = 2; else R = 1;
        unsigned long long* bins = (unsigned long long*)((char*)d_ws + off);
        hipMemsetAsync(bins, 0, (size_t)R * C * 8, stream);
        edge_atomic_kernel<<<(E + 255) / 256, 256, 0, stream>>>(eidx, owner_of,
                                                                err_node, bins,
                                                                E, C, R - 1);
        finalize_kernel<<<(C + 255) / 256, 256, 0, stream>>>(bins, (float*)d_out, C, R);
    }
}